// Round 1
// baseline (267946.631 us; speedup 1.0000x reference)
//
#include <hip/hip_runtime.h>
#include <math.h>

#define B 32
#define SEQ 1024
#define H 512
#define KFULL 1024          // D + H (both layers: 512+512)
#define NWG 192
#define NT 256
#define CHUNK 128
#define FLAG_STRIDE 16      // one flag per 64B to avoid false sharing

__device__ __forceinline__ float sigf(float v) { return 1.0f / (1.0f + expf(-v)); }

// ---------------- grid-wide barrier (flag array + go flag) ----------------
// flags[i*FLAG_STRIDE] = arrive flag of WG i ; flags[NWG*FLAG_STRIDE] = go flag.
// Monotonic generation counter, no reset needed. Agent-scope release/acquire
// handles cross-XCD L2 non-coherence (writes flushed on release, caches
// invalidated on acquire).
__device__ __forceinline__ void grid_sync(unsigned* flags, unsigned gen) {
    __syncthreads();
    const int wg = blockIdx.x;
    const int tid = threadIdx.x;
    unsigned* go = &flags[NWG * FLAG_STRIDE];
    if (tid == 0) {
        __hip_atomic_store(&flags[wg * FLAG_STRIDE], gen,
                           __ATOMIC_RELEASE, __HIP_MEMORY_SCOPE_AGENT);
    }
    if (wg == 0) {
        if (tid < NWG) {
            // acquire spin: deadlock-proof regardless of cache-bypass codegen
            while (__hip_atomic_load(&flags[tid * FLAG_STRIDE],
                                     __ATOMIC_ACQUIRE, __HIP_MEMORY_SCOPE_AGENT) < gen) {
                __builtin_amdgcn_s_sleep(1);
            }
        }
        __syncthreads();
        if (tid == 0) {
            __hip_atomic_store(go, gen, __ATOMIC_RELEASE, __HIP_MEMORY_SCOPE_AGENT);
        }
    } else {
        if (tid == 0) {
            while (__hip_atomic_load(go, __ATOMIC_ACQUIRE,
                                     __HIP_MEMORY_SCOPE_AGENT) < gen) {
                __builtin_amdgcn_s_sleep(1);
            }
        }
    }
    __syncthreads();
}

// ---------------- LDS staging of one K-chunk of the virtual xh matrix ------
// element (b, kk): k = kc + kk.  k < H -> src0[b*stride0 + k]
//                                k >= H -> src1[b*H + (k-H)]
// Layout xh[kk][b] with B+1=33 pad: stage writes (consecutive kk, fixed b)
// hit all 32 banks; compute reads xh[kk][b] are <=4-way which is cheap.
__device__ __forceinline__ void stage_chunk(float (*xh)[B + 1],
                                            const float* src0, const float* src1,
                                            int kc, size_t stride0) {
#pragma unroll
    for (int j = 0; j < (CHUNK * B) / NT; ++j) {      // 16 iters
        int idx = j * NT + (int)threadIdx.x;
        int b = idx >> 7;                 // idx / CHUNK
        int kk = idx & (CHUNK - 1);
        int k = kc + kk;
        float v = (k < H) ? src0[(size_t)b * stride0 + (size_t)k]
                          : src1[b * H + (k - H)];
        xh[kk][b] = v;
    }
}

// ---------------- persistent GRU kernel ----------------
__global__ __launch_bounds__(NT) void gru_kernel(
    const float* x,
    const float* Wz0, const float* bz0, const float* Wr0, const float* br0,
    const float* Wo0, const float* bo0,
    const float* Wz1, const float* bz1, const float* Wr1, const float* br1,
    const float* Wo1, const float* bo1,
    float* zbuf, float* rhbuf, float* xobuf, float* hbuf0, float* hbuf1,
    unsigned* flags, float* out)
{
    __shared__ float xh[CHUNK][B + 1];
    __shared__ float red[B][8][8];
    const int wg = blockIdx.x;
    const int tid = threadIdx.x;
    unsigned gen = 0;

    for (int pass = 0; pass < 2; ++pass) {
        // pass 0: x input, write y0 into out (scratch); pass 1: read y0 from out,
        // overwrite in place with y1 (phase1 reads slice t, phase2 writes slice t,
        // barrier in between -> safe).
        const float* xsrc = pass ? out : x;
        const float* Wz = pass ? Wz1 : Wz0;
        const float* bz = pass ? bz1 : bz0;
        const float* Wr = pass ? Wr1 : Wr0;
        const float* br = pass ? br1 : br0;
        const float* Wo = pass ? Wo1 : Wo0;
        const float* bo = pass ? bo1 : bo0;
        float* hbuf = pass ? hbuf1 : hbuf0;

        for (int t = 0; t < SEQ; ++t) {
            const float* xt = xsrc + (size_t)t * H;   // [b][k] at b*(SEQ*H)+k

            // ---------------- phase 1: z-pre, r-pre (K=1024), xo-pre (K=512)
            {
                const int gate = wg >> 6;            // 0:z 1:r 2:xo
                const int n0 = (wg & 63) * 8;        // 8 output cols per WG
                const float* W = (gate == 0) ? Wz : (gate == 1) ? Wr : Wo;
                const float* bias = (gate == 0) ? bz : (gate == 1) ? br : bo;
                const int K = (gate == 2) ? H : KFULL;
                const int b = tid >> 3;              // 0..31
                const int ks = tid & 7;              // K-split 8

                float acc[8];
#pragma unroll
                for (int c = 0; c < 8; ++c) acc[c] = 0.f;

                for (int kc = 0; kc < K; kc += CHUNK) {
                    stage_chunk(xh, xt, hbuf, kc, (size_t)SEQ * H);
                    __syncthreads();
                    const float* wbase = W + (size_t)(kc + ks * 16) * H + n0;
#pragma unroll 8
                    for (int i = 0; i < 16; ++i) {
                        float xv = xh[ks * 16 + i][b];
                        float4 wa = *(const float4*)(wbase + (size_t)i * H);
                        float4 wb = *(const float4*)(wbase + (size_t)i * H + 4);
                        acc[0] = fmaf(xv, wa.x, acc[0]);
                        acc[1] = fmaf(xv, wa.y, acc[1]);
                        acc[2] = fmaf(xv, wa.z, acc[2]);
                        acc[3] = fmaf(xv, wa.w, acc[3]);
                        acc[4] = fmaf(xv, wb.x, acc[4]);
                        acc[5] = fmaf(xv, wb.y, acc[5]);
                        acc[6] = fmaf(xv, wb.z, acc[6]);
                        acc[7] = fmaf(xv, wb.w, acc[7]);
                    }
                    __syncthreads();
                }
#pragma unroll
                for (int c = 0; c < 8; ++c) red[b][ks][c] = acc[c];
                __syncthreads();
                {
                    const int c = tid & 7;           // reuse b = tid>>3
                    float s = red[b][0][c];
#pragma unroll
                    for (int k2 = 1; k2 < 8; ++k2) s += red[b][k2][c];
                    const int n = n0 + c;
                    s += bias[n];
                    if (gate == 0)      zbuf[b * H + n] = sigf(s);
                    else if (gate == 1) rhbuf[b * H + n] = sigf(s) * hbuf[b * H + n];
                    else                xobuf[b * H + n] = s;
                }
            }
            grid_sync(flags, ++gen);

            // ---------------- phase 2: (r*h) @ Wo_h, tanh, gated update
            if (wg < 128) {
                const int n0 = wg * 4;               // 4 cols per WG
                const int b = tid >> 3;              // 0..31
                const int c2 = (tid >> 1) & 3;       // col within WG
                const int ks2 = tid & 1;             // K-split 2
                const int n = n0 + c2;
                const float* Woh = Wo + (size_t)H * H;   // rows 512..1023
                float acc = 0.f;
                for (int kc = 0; kc < H; kc += CHUNK) {
                    stage_chunk(xh, rhbuf, rhbuf, kc, (size_t)H);
                    __syncthreads();
#pragma unroll 8
                    for (int i = 0; i < 64; ++i) {
                        int kk = ks2 * 64 + i;
                        acc = fmaf(xh[kk][b], Woh[(size_t)(kc + kk) * H + n], acc);
                    }
                    __syncthreads();
                }
                red[b][0][c2 * 2 + ks2] = acc;
                __syncthreads();
                if (tid < 128) {
                    const int b2 = tid >> 2;
                    const int c = tid & 3;
                    const int nn = n0 + c;
                    float s = red[b2][0][c * 2] + red[b2][0][c * 2 + 1];
                    float pre = xobuf[b2 * H + nn] + s;
                    float ht = tanhf(pre);
                    float z = zbuf[b2 * H + nn];
                    float hold = hbuf[b2 * H + nn];
                    float hn = (1.f - z) * ht + z * hold;
                    hbuf[b2 * H + nn] = hn;
                    out[(size_t)b2 * SEQ * H + (size_t)t * H + nn] = hn;
                    if (t == SEQ - 1)
                        out[(size_t)B * SEQ * H + b2 * (2 * H) + pass * H + nn] = hn;
                }
            }
            grid_sync(flags, ++gen);
        }
    }
}

// ---------------- init: zero barrier flags, load h0 ----------------
__global__ void init_kernel(const float* h0, float* hbuf0, float* hbuf1,
                            unsigned* flags) {
    int idx = blockIdx.x * blockDim.x + threadIdx.x;
    int nthr = gridDim.x * blockDim.x;
    for (int i = idx; i < B * H; i += nthr) {
        int b = i >> 9, n = i & 511;
        hbuf0[i] = h0[b * 1024 + n];        // h0[b][0][n]
        hbuf1[i] = h0[b * 1024 + 512 + n];  // h0[b][1][n]
    }
    for (int i = idx; i < (NWG + 1) * FLAG_STRIDE; i += nthr) flags[i] = 0;
}

extern "C" void kernel_launch(void* const* d_in, const int* in_sizes, int n_in,
                              void* d_out, int out_size, void* d_ws, size_t ws_size,
                              hipStream_t stream) {
    const float* x   = (const float*)d_in[0];
    const float* h0  = (const float*)d_in[1];
    const float* Wz0 = (const float*)d_in[2];
    const float* bz0 = (const float*)d_in[3];
    const float* Wr0 = (const float*)d_in[4];
    const float* br0 = (const float*)d_in[5];
    const float* Wo0 = (const float*)d_in[6];
    const float* bo0 = (const float*)d_in[7];
    const float* Wz1 = (const float*)d_in[8];
    const float* bz1 = (const float*)d_in[9];
    const float* Wr1 = (const float*)d_in[10];
    const float* br1 = (const float*)d_in[11];
    const float* Wo1 = (const float*)d_in[12];
    const float* bo1 = (const float*)d_in[13];
    float* out = (float*)d_out;

    char* ws = (char*)d_ws;
    float* zbuf     = (float*)(ws);             // 64KB  [32][512]
    float* rhbuf    = (float*)(ws + 0x10000);   // 64KB
    float* xobuf    = (float*)(ws + 0x20000);   // 64KB
    float* hbuf0    = (float*)(ws + 0x30000);   // 64KB
    float* hbuf1    = (float*)(ws + 0x40000);   // 64KB
    unsigned* flags = (unsigned*)(ws + 0x50000);// (192+1)*64B

    init_kernel<<<dim3(32), dim3(256), 0, stream>>>(h0, hbuf0, hbuf1, flags);
    gru_kernel<<<dim3(NWG), dim3(NT), 0, stream>>>(
        x, Wz0, bz0, Wr0, br0, Wo0, bo0,
        Wz1, bz1, Wr1, br1, Wo1, bo1,
        zbuf, rhbuf, xobuf, hbuf0, hbuf1, flags, out);
}

// Round 3
// 183343.762 us; speedup vs baseline: 1.4614x; 1.4614x over previous
//
#include <hip/hip_runtime.h>
#include <math.h>

#define B 32
#define SEQ 1024
#define H 512
#define KFULL 1024          // D + H (both layers: 512+512)
#define NWG 192
#define NT 256
#define CHUNK 256
#define FLAG_STRIDE 16      // one flag per 64B line

__device__ __forceinline__ float sigf(float v) { return 1.0f / (1.0f + expf(-v)); }

// Relaxed agent-scope atomics: single sc0/sc1 L2-bypassing access to the
// coherent LLC. NO buffer_wbl2 / buffer_inv (those made acq/rel agent ops
// cost ~65us/barrier in round 1). Use for ALL cross-WG data.
__device__ __forceinline__ float ldc(const float* p) {
    return __hip_atomic_load(p, __ATOMIC_RELAXED, __HIP_MEMORY_SCOPE_AGENT);
}
__device__ __forceinline__ void stc(float* p, float v) {
    __hip_atomic_store(p, v, __ATOMIC_RELAXED, __HIP_MEMORY_SCOPE_AGENT);
}

// Fence-free grid barrier. Ordering: s_waitcnt vmcnt(0) guarantees prior
// relaxed stores have been acknowledged by the LLC (coherence point) before
// the arrive-flag store is issued. Readers' relaxed loads bypass L1/L2, so
// they observe the data with no invalidate needed.
__device__ __forceinline__ void grid_sync(unsigned* flags, unsigned gen) {
    asm volatile("s_waitcnt vmcnt(0)" ::: "memory");
    __syncthreads();
    const int tid = threadIdx.x;
    if (tid == 0) {
        __hip_atomic_store(&flags[blockIdx.x * FLAG_STRIDE], gen,
                           __ATOMIC_RELAXED, __HIP_MEMORY_SCOPE_AGENT);
    }
    if (blockIdx.x == 0) {
        if (tid < NWG) {
            while (__hip_atomic_load(&flags[tid * FLAG_STRIDE],
                                     __ATOMIC_RELAXED, __HIP_MEMORY_SCOPE_AGENT) < gen) {
                __builtin_amdgcn_s_sleep(1);
            }
        }
        __syncthreads();
        if (tid == 0) {
            __hip_atomic_store(&flags[NWG * FLAG_STRIDE], gen,
                               __ATOMIC_RELAXED, __HIP_MEMORY_SCOPE_AGENT);
        }
    } else if (tid == 0) {
        while (__hip_atomic_load(&flags[NWG * FLAG_STRIDE],
                                 __ATOMIC_RELAXED, __HIP_MEMORY_SCOPE_AGENT) < gen) {
            __builtin_amdgcn_s_sleep(1);
        }
    }
    __syncthreads();
}

// Stage one K-chunk of the virtual [x, h] matrix into LDS as xh[kk][b].
// COH0: src0 is cross-WG data (needs coherent loads). src1 (h) always is.
template <bool COH0>
__device__ __forceinline__ void stage_chunk(float (*xh)[B + 1],
                                            const float* src0, const float* src1,
                                            int kc, size_t stride0) {
#pragma unroll
    for (int j = 0; j < (CHUNK * B) / NT; ++j) {      // 32 iters
        int idx = j * NT + (int)threadIdx.x;
        int b = idx >> 8;                 // idx / CHUNK
        int kk = idx & (CHUNK - 1);
        int k = kc + kk;
        float v;
        if (k < H) {
            const float* p = src0 + (size_t)b * stride0 + (size_t)k;
            v = COH0 ? ldc(p) : *p;
        } else {
            v = ldc(src1 + b * H + (k - H));
        }
        xh[kk][b] = v;
    }
}

template <bool P1>
__device__ __forceinline__ void run_pass(
    const float* xsrc,
    const float* Wz, const float* bz, const float* Wr, const float* br,
    const float* Wo, const float* bo,
    float* zbuf, float* rhbuf, float* xobuf, float* hbuf,
    unsigned* flags, float* out, unsigned& gen,
    float (*xh)[B + 1], float (*red)[8][8])
{
    const int wg = blockIdx.x;
    const int tid = threadIdx.x;

    for (int t = 0; t < SEQ; ++t) {
        const float* xt = xsrc + (size_t)t * H;   // [b][k] at b*(SEQ*H)+k

        // ---------------- phase 1: z-pre, r-pre (K=1024), xo-pre (K=512)
        {
            const int gate = wg >> 6;            // 0:z 1:r 2:xo
            const int n0 = (wg & 63) * 8;        // 8 output cols per WG
            const float* W = (gate == 0) ? Wz : (gate == 1) ? Wr : Wo;
            const float* bias = (gate == 0) ? bz : (gate == 1) ? br : bo;
            const int K = (gate == 2) ? H : KFULL;
            const int b = tid >> 3;              // 0..31
            const int ks = tid & 7;              // K-split 8

            float acc[8];
#pragma unroll
            for (int c = 0; c < 8; ++c) acc[c] = 0.f;

            for (int kc = 0; kc < K; kc += CHUNK) {
                stage_chunk<P1>(xh, xt, hbuf, kc, (size_t)SEQ * H);
                __syncthreads();
                const float* wbase = W + (size_t)(kc + ks * 32) * H + n0;
#pragma unroll 8
                for (int i = 0; i < 32; ++i) {
                    int ii = (i + ks * 4) & 31;   // rotate: banks spread across ks
                    float xv = xh[ks * 32 + ii][b];
                    const float* wrow = wbase + (size_t)ii * H;
                    float4 wa = *(const float4*)(wrow);
                    float4 wb = *(const float4*)(wrow + 4);
                    acc[0] = fmaf(xv, wa.x, acc[0]);
                    acc[1] = fmaf(xv, wa.y, acc[1]);
                    acc[2] = fmaf(xv, wa.z, acc[2]);
                    acc[3] = fmaf(xv, wa.w, acc[3]);
                    acc[4] = fmaf(xv, wb.x, acc[4]);
                    acc[5] = fmaf(xv, wb.y, acc[5]);
                    acc[6] = fmaf(xv, wb.z, acc[6]);
                    acc[7] = fmaf(xv, wb.w, acc[7]);
                }
                __syncthreads();
            }
#pragma unroll
            for (int c = 0; c < 8; ++c) red[b][ks][c] = acc[c];
            __syncthreads();
            {
                const int c = tid & 7;
                float s = red[b][0][c];
#pragma unroll
                for (int k2 = 1; k2 < 8; ++k2) s += red[b][k2][c];
                const int n = n0 + c;
                s += bias[n];
                if (gate == 0)      stc(&zbuf[b * H + n], sigf(s));
                else if (gate == 1) stc(&rhbuf[b * H + n], sigf(s) * ldc(&hbuf[b * H + n]));
                else                stc(&xobuf[b * H + n], s);
            }
        }
        grid_sync(flags, ++gen);

        // ---------------- phase 2: (r*h) @ Wo_h, tanh, gated update
        if (wg < 128) {
            const int n0 = wg * 4;               // 4 cols per WG
            const int b = tid >> 3;              // 0..31
            const int c2 = (tid >> 1) & 3;       // col within WG
            const int ks2 = tid & 1;             // K-split 2
            const int n = n0 + c2;
            const float* Woh = Wo + (size_t)H * H;   // rows 512..1023
            float acc = 0.f;
            for (int kc = 0; kc < H; kc += CHUNK) {
                stage_chunk<true>(xh, rhbuf, rhbuf, kc, (size_t)H);
                __syncthreads();
#pragma unroll 8
                for (int i = 0; i < 128; ++i) {
                    int kk = ks2 * 128 + i;
                    acc = fmaf(xh[kk][b], Woh[(size_t)(kc + kk) * H + n], acc);
                }
                __syncthreads();
            }
            red[b][0][c2 * 2 + ks2] = acc;
            __syncthreads();
            if (tid < 128) {
                const int b2 = tid >> 2;
                const int c = tid & 3;
                const int nn = n0 + c;
                float s = red[b2][0][c * 2] + red[b2][0][c * 2 + 1];
                float pre = ldc(&xobuf[b2 * H + nn]) + s;
                float ht = tanhf(pre);
                float z = ldc(&zbuf[b2 * H + nn]);
                float hold = ldc(&hbuf[b2 * H + nn]);
                float hn = (1.f - z) * ht + z * hold;
                stc(&hbuf[b2 * H + nn], hn);
                stc(&out[(size_t)b2 * SEQ * H + (size_t)t * H + nn], hn);
                if (t == SEQ - 1)
                    stc(&out[(size_t)B * SEQ * H + b2 * (2 * H) + (P1 ? 1 : 0) * H + nn], hn);
            }
        }
        grid_sync(flags, ++gen);
    }
}

__global__ __launch_bounds__(NT) void gru_kernel(
    const float* x,
    const float* Wz0, const float* bz0, const float* Wr0, const float* br0,
    const float* Wo0, const float* bo0,
    const float* Wz1, const float* bz1, const float* Wr1, const float* br1,
    const float* Wo1, const float* bo1,
    float* zbuf, float* rhbuf, float* xobuf, float* hbuf0, float* hbuf1,
    unsigned* flags, float* out)
{
    __shared__ float xh[CHUNK][B + 1];
    __shared__ float red[B][8][8];
    unsigned gen = 0;

    run_pass<false>(x,   Wz0, bz0, Wr0, br0, Wo0, bo0,
                    zbuf, rhbuf, xobuf, hbuf0, flags, out, gen, xh, red);
    run_pass<true>(out, Wz1, bz1, Wr1, br1, Wo1, bo1,
                   zbuf, rhbuf, xobuf, hbuf1, flags, out, gen, xh, red);
}

__global__ void init_kernel(const float* h0, float* hbuf0, float* hbuf1,
                            unsigned* flags) {
    int idx = blockIdx.x * blockDim.x + threadIdx.x;
    int nthr = gridDim.x * blockDim.x;
    for (int i = idx; i < B * H; i += nthr) {
        int b = i >> 9, n = i & 511;
        hbuf0[i] = h0[b * 1024 + n];        // h0[b][0][n]
        hbuf1[i] = h0[b * 1024 + 512 + n];  // h0[b][1][n]
    }
    for (int i = idx; i < (NWG + 1) * FLAG_STRIDE; i += nthr) flags[i] = 0;
}

extern "C" void kernel_launch(void* const* d_in, const int* in_sizes, int n_in,
                              void* d_out, int out_size, void* d_ws, size_t ws_size,
                              hipStream_t stream) {
    const float* x   = (const float*)d_in[0];
    const float* h0  = (const float*)d_in[1];
    const float* Wz0 = (const float*)d_in[2];
    const float* bz0 = (const float*)d_in[3];
    const float* Wr0 = (const float*)d_in[4];
    const float* br0 = (const float*)d_in[5];
    const float* Wo0 = (const float*)d_in[6];
    const float* bo0 = (const float*)d_in[7];
    const float* Wz1 = (const float*)d_in[8];
    const float* bz1 = (const float*)d_in[9];
    const float* Wr1 = (const float*)d_in[10];
    const float* br1 = (const float*)d_in[11];
    const float* Wo1 = (const float*)d_in[12];
    const float* bo1 = (const float*)d_in[13];
    float* out = (float*)d_out;

    char* ws = (char*)d_ws;
    float* zbuf     = (float*)(ws);             // 64KB  [32][512]
    float* rhbuf    = (float*)(ws + 0x10000);   // 64KB
    float* xobuf    = (float*)(ws + 0x20000);   // 64KB
    float* hbuf0    = (float*)(ws + 0x30000);   // 64KB
    float* hbuf1    = (float*)(ws + 0x40000);   // 64KB
    unsigned* flags = (unsigned*)(ws + 0x50000);// (192+1)*64B

    init_kernel<<<dim3(32), dim3(256), 0, stream>>>(h0, hbuf0, hbuf1, flags);
    gru_kernel<<<dim3(NWG), dim3(NT), 0, stream>>>(
        x, Wz0, bz0, Wr0, br0, Wo0, bo0,
        Wz1, bz1, Wr1, br1, Wo1, bo1,
        zbuf, rhbuf, xobuf, hbuf0, hbuf1, flags, out);
}